// Round 9
// baseline (191.483 us; speedup 1.0000x reference)
//
#include <hip/hip_runtime.h>
#include <math.h>

// SimpleSplitFF: sparse expert-choice MoE.
// x:(4,4096,1024) f32, controller:(1024,32), f1:(1024,32,128), bias:(32,128), f2:(32,128,1024)
// perm is one-hot over g per (b,t,e) scaled by softmax-over-g prob -> only 512 routed rows.
// Pipeline: k_zero | k_logits (dbuf GEMM only) -> k_route -> k_up -> k_down.
// ~125us of dur_us is harness ws-poison fills (measured r8) — untouchable floor.

#define DM   1024
#define NE   32
#define FE   128
#define T4   4
#define SS   4096
#define NGRP 1024
#define NROW 512                       // route rows r = (b*4+t)*32+e = row16*32+e
#define LP_STRIDE (NROW * NGRP)        // one K-split partial (2 MiB)
#define VP_OFF   524288                // Vp partials: aliases Lp splits 1-2 (dead after route)

// ---------------------------------------------------------------------------
// K0: zero d_out at fill-rate (fillBuffer shape: pure coalesced stores).
// 2048 blocks x 256 thr x 8 float4 = exactly 4*4096*1024 floats.
// ---------------------------------------------------------------------------
__global__ __launch_bounds__(256)
void k_zero(float* __restrict__ out)
{
    const float4 z = make_float4(0.f, 0.f, 0.f, 0.f);
    float4* o4 = (float4*)out + (size_t)blockIdx.x * 2048;
#pragma unroll
    for (int j = 0; j < 8; ++j) o4[j * 256 + threadIdx.x] = z;
}

// ---------------------------------------------------------------------------
// K1: partial logits Lp[ks][row][g].  grid (256,4) = 1024 blocks x 128 thr.
// 64-token tile x 256-d K-split; thread tile 4tok x 4e; 32-d kits, LDS
// double-buffered (25.6 KB -> up to 6 blocks/CU). No zero-fill here.
// ---------------------------------------------------------------------------
__global__ __launch_bounds__(128, 3)
void k_logits(const float* __restrict__ x, const float* __restrict__ ctrl,
              float* __restrict__ Lp)
{
    const int m      = blockIdx.x;
    const int ks     = blockIdx.y;
    const int tid    = threadIdx.x;
    const int base_s = m * 64;                 // never straddles b (64 | 4096)
    const int b      = base_s >> 12;
    const int g0     = (base_s & 4095) >> 2;

    __shared__ float xT[2][32 * 68];   // [buf][d][tok], pad 68
    __shared__ float cs[2][32 * 32];   // [buf][d][e]

    const int tq = tid & 15;           // token quad (group g0+tq)
    const int eg = tid >> 4;           // 0..7 -> experts eg*4..+3

    float acc[4][4];
#pragma unroll
    for (int i = 0; i < 4; ++i)
#pragma unroll
        for (int j = 0; j < 4; ++j) acc[i][j] = 0.f;

    // staging map: srow = tid>>1 (0..63), sq = tid&1 -> f4-cols sq*4..+3 of 8
    const int srow = tid >> 1;
    const int sq   = tid & 1;
    const float* xrow = x + (size_t)(base_s + srow) * DM + ks * 256 + sq * 16;

    float4 px[4];                      // x prefetch: 4 f4 = 16 d-floats
    float4 pc[2];                      // ctrl prefetch: 2 f4 (256 f4/kit, 128 thr)

    {   // prologue: load + store kit 0
#pragma unroll
        for (int cr = 0; cr < 4; ++cr) px[cr] = *(const float4*)(xrow + cr * 4);
        const float4* cg = (const float4*)(ctrl + (size_t)(ks * 256) * NE);
        pc[0] = cg[tid]; pc[1] = cg[tid + 128];
#pragma unroll
        for (int cr = 0; cr < 4; ++cr) {
            const int d = (sq * 4 + cr) * 4;
            const float4 v = px[cr];
            xT[0][(d + 0) * 68 + srow] = v.x;
            xT[0][(d + 1) * 68 + srow] = v.y;
            xT[0][(d + 2) * 68 + srow] = v.z;
            xT[0][(d + 3) * 68 + srow] = v.w;
        }
        ((float4*)cs[0])[tid]       = pc[0];
        ((float4*)cs[0])[tid + 128] = pc[1];
    }
    __syncthreads();

    for (int kit = 0; kit < 8; ++kit) {
        if (kit < 7) {                 // issue next kit's global loads
            const int koff = (kit + 1) * 32;
#pragma unroll
            for (int cr = 0; cr < 4; ++cr)
                px[cr] = *(const float4*)(xrow + koff + cr * 4);
            const float4* cg = (const float4*)(ctrl + (size_t)(ks * 256 + koff) * NE);
            pc[0] = cg[tid]; pc[1] = cg[tid + 128];
        }

        const float* xb = xT[kit & 1];
        const float* cb = cs[kit & 1];
#pragma unroll 8
        for (int d = 0; d < 32; ++d) {
            const float4 xv = *(const float4*)(xb + d * 68 + tq * 4);
            const float4 cv = *(const float4*)(cb + d * 32 + eg * 4);
            const float xa[4] = { xv.x, xv.y, xv.z, xv.w };
            const float ca[4] = { cv.x, cv.y, cv.z, cv.w };
#pragma unroll
            for (int i = 0; i < 4; ++i)
#pragma unroll
                for (int j = 0; j < 4; ++j) acc[i][j] += xa[i] * ca[j];
        }

        if (kit < 7) {                 // store into the other buffer
            const int nb = (kit + 1) & 1;
#pragma unroll
            for (int cr = 0; cr < 4; ++cr) {
                const int d = (sq * 4 + cr) * 4;
                const float4 v = px[cr];
                xT[nb][(d + 0) * 68 + srow] = v.x;
                xT[nb][(d + 1) * 68 + srow] = v.y;
                xT[nb][(d + 2) * 68 + srow] = v.z;
                xT[nb][(d + 3) * 68 + srow] = v.w;
            }
            ((float4*)cs[nb])[tid]       = pc[0];
            ((float4*)cs[nb])[tid + 128] = pc[1];
        }
        __syncthreads();
    }

    {   // write partial logits (lanes 0..15 -> consecutive g)
        float* Lb = Lp + (size_t)ks * LP_STRIDE;
        const int g = g0 + tq;
#pragma unroll
        for (int i = 0; i < 4; ++i)
#pragma unroll
            for (int j = 0; j < 4; ++j) {
                const int row = (b * T4 + i) * NE + eg * 4 + j;
                Lb[(size_t)row * NGRP + g] = acc[i][j];
            }
    }
}

// ---------------------------------------------------------------------------
// K2: route. grid 512 blocks x 256 thr (one block per row). Sums 4
// K-partials, online softmax+argmax over g. Stores g (int bits) at
// Lp[row][0], p at Lp[row][1] (block r touches only row r -> no races).
// ---------------------------------------------------------------------------
__global__ __launch_bounds__(256)
void k_route(float* __restrict__ Lp)
{
    __shared__ float rmx[4], rs[4];
    __shared__ int   rgm[4];

    const int r   = blockIdx.x;
    const int tid = threadIdx.x;
    const float* L0 = Lp + (size_t)r * NGRP;

    const int g0c = tid * 4;
    const float4 v0 = *(const float4*)(L0 + g0c);
    const float4 v1 = *(const float4*)(L0 + 1 * LP_STRIDE + g0c);
    const float4 v2 = *(const float4*)(L0 + 2 * LP_STRIDE + g0c);
    const float4 v3 = *(const float4*)(L0 + 3 * LP_STRIDE + g0c);
    const float l[4] = { v0.x + v1.x + v2.x + v3.x,
                         v0.y + v1.y + v2.y + v3.y,
                         v0.z + v1.z + v2.z + v3.z,
                         v0.w + v1.w + v2.w + v3.w };
    float mx = -INFINITY, s = 0.f;
    int gm = 0;
#pragma unroll
    for (int j = 0; j < 4; ++j) {
        const float lv = l[j];
        if (lv > mx) { s = s * __expf(mx - lv) + 1.f; mx = lv; gm = g0c + j; }
        else         { s += __expf(lv - mx); }
    }
#pragma unroll
    for (int off = 1; off < 64; off <<= 1) {
        const float m2 = __shfl_xor(mx, off);
        const float s2 = __shfl_xor(s, off);
        const int   g2 = __shfl_xor(gm, off);
        const float mn = fmaxf(mx, m2);
        s  = s * __expf(mx - mn) + s2 * __expf(m2 - mn);
        gm = (m2 > mx) ? g2 : ((m2 == mx && g2 < gm) ? g2 : gm);
        mx = mn;
    }
    if ((tid & 63) == 0) {
        const int w = tid >> 6;
        rmx[w] = mx; rs[w] = s; rgm[w] = gm;
    }
    __syncthreads();
    if (tid == 0) {
        float M = rmx[0], S = rs[0];
        int   G = rgm[0];
#pragma unroll
        for (int wv = 1; wv < 4; ++wv) {
            const float m2 = rmx[wv], s2 = rs[wv];
            const int   g2 = rgm[wv];
            const float mn = fmaxf(M, m2);
            S = S * __expf(M - mn) + s2 * __expf(m2 - mn);
            G = (m2 > M) ? g2 : ((m2 == M && g2 < G) ? g2 : G);
            M = mn;
        }
        ((int*)Lp)[(size_t)r * NGRP] = G;
        Lp[(size_t)r * NGRP + 1] = 1.f / S;
    }
}

// ---------------------------------------------------------------------------
// K3: up-projection partials. grid 512 = (dc 16)<<5 | (e 32), 256 thr.
// All 16 rows per block (f1 slice read once, shared by 2 rows/thread).
// Vp[dc*32+e][row16][f].
// ---------------------------------------------------------------------------
__global__ __launch_bounds__(256, 2)
void k_up(const float* __restrict__ x, const float* __restrict__ f1,
          float* __restrict__ ws)
{
    const int e   = blockIdx.x & 31;
    const int dc  = blockIdx.x >> 5;           // 64-d chunk
    const int tid = threadIdx.x;

    __shared__ float xs[16 * 68];
    __shared__ int   gS[16];

    if (tid < 16) {
        const int r = tid * NE + e;            // row16*32+e
        gS[tid] = ((const int*)ws)[(size_t)r * NGRP];
    }
    __syncthreads();

    {   // stage 16 rows x 64 d: one f4/thread
        const int row = tid >> 4;
        const int f4c = tid & 15;
        const int bq = row >> 2, t = row & 3;
        const int s = bq * SS + gS[row] * 4 + t;
        const float4 v = *(const float4*)(x + (size_t)s * DM + dc * 64 + f4c * 4);
        xs[row * 68 + f4c * 4 + 0] = v.x;
        xs[row * 68 + f4c * 4 + 1] = v.y;
        xs[row * 68 + f4c * 4 + 2] = v.z;
        xs[row * 68 + f4c * 4 + 3] = v.w;
    }
    __syncthreads();

    const int f4 = tid & 31;                   // 4 f's
    const int rw = tid >> 5;                   // rows rw, rw+8
    const float* f1p = f1 + (size_t)(dc * 64) * (NE * FE) + e * FE + f4 * 4;
    const float* x0 = xs + rw * 68;
    const float* x1 = xs + (rw + 8) * 68;

    float a0[4] = {0.f, 0.f, 0.f, 0.f}, a1[4] = {0.f, 0.f, 0.f, 0.f};
#pragma unroll 16
    for (int dl = 0; dl < 64; ++dl) {
        const float4 w4 = *(const float4*)(f1p + (size_t)dl * (NE * FE));
        const float xa = x0[dl], xb = x1[dl];
        a0[0] += xa * w4.x; a0[1] += xa * w4.y; a0[2] += xa * w4.z; a0[3] += xa * w4.w;
        a1[0] += xb * w4.x; a1[1] += xb * w4.y; a1[2] += xb * w4.z; a1[3] += xb * w4.w;
    }

    float* Vp = ws + VP_OFF + (size_t)(dc * 32 + e) * (16 * FE);
    *(float4*)(Vp + rw       * FE + f4 * 4) = make_float4(a0[0], a0[1], a0[2], a0[3]);
    *(float4*)(Vp + (rw + 8) * FE + f4 * 4) = make_float4(a1[0], a1[1], a1[2], a1[3]);
}

// ---------------------------------------------------------------------------
// K4: fused reduce + group-coupled relu + down-projection + atomic scatter.
// grid 512 = (rh 2)<<8 | (dt 8)<<5 | (e 32). Block: 8 rows x 128-d tile.
// ---------------------------------------------------------------------------
__global__ __launch_bounds__(256, 2)
void k_down(const float* __restrict__ f2, const float* __restrict__ bias,
            const float* __restrict__ ws, float* __restrict__ out)
{
    const int e   = blockIdx.x & 31;
    const int dt  = (blockIdx.x >> 5) & 7;     // 128-d output tile
    const int rh  = blockIdx.x >> 8;           // rows rh*8..+7 (2 full b-quads)
    const int tid = threadIdx.x;

    __shared__ float vv[8 * 132];
    __shared__ float hs[8 * 132];
    __shared__ int   gS[8];
    __shared__ float pS[8];

    if (tid < 8) {
        const int r = (rh * 8 + tid) * NE + e;
        gS[tid] = ((const int*)ws)[(size_t)r * NGRP];
        pS[tid] = ws[(size_t)r * NGRP + 1];
    }

    {   // reduce 16 K-chunk partials: one f4-output per thread (row*32+f4)
        const float* Vp = ws + VP_OFF;
        const int row = tid >> 5, f4 = tid & 31;
        float4 s = make_float4(0.f, 0.f, 0.f, 0.f);
#pragma unroll
        for (int dc = 0; dc < 16; ++dc) {
            const float4 v = *(const float4*)(Vp + (size_t)(dc * 32 + e) * (16 * FE)
                                                 + (rh * 8 + row) * FE + f4 * 4);
            s.x += v.x; s.y += v.y; s.z += v.z; s.w += v.w;
        }
        *(float4*)(vv + row * 132 + f4 * 4) = s;
    }
    __syncthreads();

    {   // group-coupled relu, p_t folded; quads are local rows {0..3},{4..7}
#pragma unroll
        for (int q = 0; q < 4; ++q) {
            const int idx = tid + q * 256;     // row*128 + f
            const int row = idx >> 7, f = idx & 127;
            const int qb = row & ~3;
            float u = bias[e * FE + f];
#pragma unroll
            for (int t2 = 0; t2 < T4; ++t2)
                if (gS[qb + t2] == gS[row]) u += pS[qb + t2] * vv[(qb + t2) * 132 + f];
            hs[row * 132 + f] = pS[row] * fmaxf(u, 0.f);
        }
    }
    __syncthreads();

    const int d4 = tid & 31;                   // 4 d's
    const int rw = tid >> 5;                   // local row 0..7
    const float* f2p = f2 + (size_t)e * FE * DM + dt * 128 + d4 * 4;
    const float* hp  = hs + rw * 132;

    float a[4] = {0.f, 0.f, 0.f, 0.f};
#pragma unroll 16
    for (int f = 0; f < FE; ++f) {
        const float4 w4 = *(const float4*)(f2p + (size_t)f * DM);
        const float ha = hp[f];
        a[0] += ha * w4.x; a[1] += ha * w4.y; a[2] += ha * w4.z; a[3] += ha * w4.w;
    }

    const int grow = rh * 8 + rw;
    const int bq = grow >> 2, t = grow & 3;
    float* orow = out + ((size_t)(bq * SS + gS[rw] * 4 + t)) * DM + dt * 128 + d4 * 4;
    atomicAdd(orow + 0, a[0]);
    atomicAdd(orow + 1, a[1]);
    atomicAdd(orow + 2, a[2]);
    atomicAdd(orow + 3, a[3]);
}

// ---------------------------------------------------------------------------
extern "C" void kernel_launch(void* const* d_in, const int* in_sizes, int n_in,
                              void* d_out, int out_size, void* d_ws, size_t ws_size,
                              hipStream_t stream)
{
    const float* x    = (const float*)d_in[0];
    const float* ctrl = (const float*)d_in[1];
    const float* f1   = (const float*)d_in[2];
    const float* bias = (const float*)d_in[3];
    const float* f2   = (const float*)d_in[4];
    float* out = (float*)d_out;
    float* ws  = (float*)d_ws;             // 8 MiB (Lp 4 splits; Vp aliases splits 1-2)

    k_zero  <<<dim3(2048),   256, 0, stream>>>(out);
    k_logits<<<dim3(256, 4), 128, 0, stream>>>(x, ctrl, ws);
    k_route <<<dim3(512),    256, 0, stream>>>(ws);
    k_up    <<<dim3(512),    256, 0, stream>>>(x, f1, ws);
    k_down  <<<dim3(512),    256, 0, stream>>>(f2, bias, ws, out);
}